// Round 2
// baseline (200.642 us; speedup 1.0000x reference)
//
#include <hip/hip_runtime.h>
#include <hip/hip_fp16.h>

#define B_ 1024
#define L_ 1024
#define NCAT_ 20
#define NNUM_ 10
#define E_ 32
#define A_ 128
#define H_ 256
#define TOPK_ 30
#define INV_SQRT_A 0.08838834764831845f

typedef _Float16 half8 __attribute__((ext_vector_type(8)));
typedef float f32x4 __attribute__((ext_vector_type(4)));

// monotonic float<->u32 (roundtrip exact)
__device__ __forceinline__ unsigned sortable(float f) {
    unsigned u = __float_as_uint(f);
    return (u & 0x80000000u) ? ~u : (u | 0x80000000u);
}
__device__ __forceinline__ float unsortable(unsigned s) {
    unsigned u = (s & 0x80000000u) ? (s ^ 0x80000000u) : ~s;
    return __uint_as_float(u);
}
__device__ __forceinline__ half8 cvt_h8(const float4 u, const float4 v) {
    half8 a;
    a[0] = (_Float16)u.x; a[1] = (_Float16)u.y;
    a[2] = (_Float16)u.z; a[3] = (_Float16)u.w;
    a[4] = (_Float16)v.x; a[5] = (_Float16)v.y;
    a[6] = (_Float16)v.z; a[7] = (_Float16)v.w;
    return a;
}

// ---------------------------------------------------------------------------
// K1: multi-role fused kernel (grid 1356 x 256).
// R12: tail branches now emit TRANSPOSED f16 weights WT[n][k] for the MFMA
// MLP kernel (WmlpT [256][128]; W1T/W2T/WpT [256][256] per qnn).  B-fragment
// of v_mfma_f32_16x16x32_f16 wants 8 contiguous k-elements per lane -> one
// 16 B load from the [n][k] layout.
// ---------------------------------------------------------------------------
#define K1_GRID 1356
__global__ __launch_bounds__(256) void fused_prep_kernel(
    const int* __restrict__ cats, const float* __restrict__ nums,
    const int* __restrict__ tgt_ids, const float* __restrict__ cat_emb,
    const float* __restrict__ Wnum, const float* __restrict__ bnum,
    const float* __restrict__ Wq, const float* __restrict__ Wk,
    const float* __restrict__ Wv, const float* __restrict__ Wo,
    const float* __restrict__ Wpool, const float* __restrict__ bpool,
    const float* __restrict__ seq_emb, const float* __restrict__ Wmlp,
    const float* __restrict__ q1W1, const float* __restrict__ q1W2,
    const float* __restrict__ q1Wp,
    const float* __restrict__ q2W1, const float* __restrict__ q2W2,
    const float* __restrict__ q2Wp,
    float* __restrict__ p_out, float* __restrict__ fused, float* __restrict__ M,
    __half2* __restrict__ seq_h2,
    __half* __restrict__ WmlpT,
    __half* __restrict__ W1T1, __half* __restrict__ W2T1, __half* __restrict__ WpT1,
    __half* __restrict__ W1T2, __half* __restrict__ W2T2, __half* __restrict__ WpT2)
{
    const int blk = blockIdx.x;
    const int t = threadIdx.x;

    if (blk < 256) {
        __shared__ float ce[4][NCAT_ * E_];
        __shared__ float tg[4][E_];
        __shared__ float nm[4][NNUM_];
        __shared__ float qs[4][A_];
        __shared__ float part[8][4][E_];
        const int r0 = blk * 4;

        for (int idx = t; idx < 640; idx += 256) {
            const int q = idx >> 3, f4 = idx & 7;
            const int row = q / 20, cat = q % 20;
            const int tok = cats[(r0 + row) * NCAT_ + cat];
            ((float4*)&ce[row][cat * 32])[f4] =
                ((const float4*)(cat_emb + (size_t)tok * 32))[f4];
        }
        if (t < 32) {
            const int row = t >> 3, f4 = t & 7;
            const int tok = tgt_ids[r0 + row];
            ((float4*)&tg[row][0])[f4] =
                ((const float4*)(cat_emb + (size_t)tok * 32))[f4];
        }
        if (t >= 64 && t < 104) {
            const int x = t - 64;
            nm[x / 10][x % 10] = nums[(r0 + x / 10) * NNUM_ + x % 10];
        }
        __syncthreads();

        {
            const int w = t >> 6, lane = t & 63;
            float q0 = 0.f, q1 = 0.f;
#pragma unroll
            for (int e = 0; e < E_; ++e) {
                float te = tg[w][e];
                q0 += te * Wq[e * A_ + lane];
                q1 += te * Wq[e * A_ + lane + 64];
            }
            qs[w][lane] = q0; qs[w][lane + 64] = q1;
        }

        {
            const int iseg = t >> 5;
            const int row = (t >> 3) & 3;
            const int c0 = (t & 7) * 4;
            float4 acc = make_float4(0.f, 0.f, 0.f, 0.f);
            const int i0 = iseg * 80;
            for (int i = i0; i < i0 + 80; ++i) {
                float4 wv = *(const float4*)(Wpool + i * 32 + c0);
                acc.x += ce[row][i] * wv.x; acc.y += ce[row][i] * wv.y;
                acc.z += ce[row][i] * wv.z; acc.w += ce[row][i] * wv.w;
            }
            *(float4*)&part[iseg][row][c0] = acc;
        }
        __syncthreads();

        if (t < 128) {
            const int row = t >> 5, c = t & 31;
            const int b = r0 + row;
            float s = bpool[c];
#pragma unroll
            for (int g = 0; g < 8; ++g) s += part[g][row][c];
            fused[b * 128 + 64 + c] = s;
            fused[b * 128 + c] = tg[row][c];

            float ne = bnum[c];
#pragma unroll
            for (int n = 0; n < NNUM_; ++n) ne += nm[row][n] * Wnum[n * 32 + c];
            fused[b * 128 + 96 + c] = ne;

            float pv = 0.f;
#pragma unroll 8
            for (int a = 0; a < A_; ++a) pv += Wk[c * A_ + a] * qs[row][a];
            p_out[b * 32 + c] = pv;
        }
        return;
    }

    if (blk < 1280) {
        int x = (blk - 256) * 256 + t;
        for (; x < 800016; x += 1024 * 256) {
            float2 v = ((const float2*)seq_emb)[x];
            seq_h2[x] = __float22half2_rn(v);
        }
        return;
    }

    if (blk < 1284) {
        const int o = (blk - 1280) * 256 + t;
        const int j = o >> 5, e = o & 31;
        float sm = 0.f;
#pragma unroll 8
        for (int a = 0; a < A_; ++a) sm += Wv[j * A_ + a] * Wo[a * E_ + e];
        M[o] = sm;
        return;
    }

    // ---- transpose-convert weights to [n][k] f16 (blocks 1284..1355)
    // chunk = 8 consecutive k for one n.  Wmlp: 256n x 16kc = 4096 chunks;
    // each 256x256 matrix: 256n x 32kc = 8192 chunks; 6 matrices.
    {
        int c = (blk - 1284) * 256 + t;          // 0 .. 18431
        for (; c < 53248; c += 72 * 256) {
            const float* src; __half* dst;
            int n, k0, K;
            if (c < 4096) {
                n = c >> 4; k0 = (c & 15) << 3; K = 128;
                src = Wmlp; dst = WmlpT;
            } else {
                const int c2 = c - 4096;
                const int m = c2 >> 13, idx = c2 & 8191;
                n = idx >> 5; k0 = (idx & 31) << 3; K = 256;
                switch (m) {
                    case 0: src = q1W1; dst = W1T1; break;
                    case 1: src = q1W2; dst = W2T1; break;
                    case 2: src = q1Wp; dst = WpT1; break;
                    case 3: src = q2W1; dst = W1T2; break;
                    case 4: src = q2W2; dst = W2T2; break;
                    default: src = q2Wp; dst = WpT2; break;
                }
            }
            float v[8];
#pragma unroll
            for (int i = 0; i < 8; ++i) v[i] = src[(size_t)(k0 + i) * 256 + n];
            float4 wq;
            __half2* hp = (__half2*)&wq;
            hp[0] = __float22half2_rn(make_float2(v[0], v[1]));
            hp[1] = __float22half2_rn(make_float2(v[2], v[3]));
            hp[2] = __float22half2_rn(make_float2(v[4], v[5]));
            hp[3] = __float22half2_rn(make_float2(v[6], v[7]));
            *(float4*)(dst + (size_t)n * K + k0) = wq;
        }
    }
}

// ---------------------------------------------------------------------------
// K2a: scores + top-30 + softmax + interest.  RM=2, grid 512 (phases A+B of
// R11, numerically proven there).  Interest goes straight to fused[b][32..63]
// in global; the MLP is a separate MFMA kernel.
// ---------------------------------------------------------------------------
#define RM 2
__global__ __launch_bounds__(512) void score_topk_kernel(
    const int* __restrict__ seqs, const __half* __restrict__ seq_h,
    const float* __restrict__ seq_emb, const float* __restrict__ p,
    const float* __restrict__ M, const float* __restrict__ bo,
    float* __restrict__ fused)
{
    const int b0 = blockIdx.x * RM;
    const int tid = threadIdx.x;

    __shared__ float sc[RM][L_];          // 8 KB (score rows; reused as ebar)
    __shared__ float ps[RM][E_];
    __shared__ float sw[RM][32];
    __shared__ int   stok[RM][32];

    if (tid < RM * 32)
        ps[tid >> 5][tid & 31] = p[(b0 + (tid >> 5)) * 32 + (tid & 31)];
    __syncthreads();

    // ---- Phase A: scores. row = tid>>8, 256 threads/row, 4 tokens/thread
    {
        const int row = tid >> 8;
        const int s = tid & 255;
        const int bb = b0 + row;
#pragma unroll
        for (int jj = 0; jj < 2; ++jj) {
            const int l1 = jj * 512 + s;
            const int l2 = l1 + 256;
            const int tok1 = seqs[bb * L_ + l1];
            const int tok2 = seqs[bb * L_ + l2];
            float4 buf[2][4];
            const float4* r1 = (const float4*)(seq_h + (size_t)tok1 * 32);
            const float4* r2 = (const float4*)(seq_h + (size_t)tok2 * 32);
#pragma unroll
            for (int i = 0; i < 4; ++i) buf[0][i] = r1[i];
#pragma unroll
            for (int i = 0; i < 4; ++i) buf[1][i] = r2[i];

            float acc0 = 0.f, acc1 = 0.f;
#pragma unroll
            for (int i = 0; i < 4; ++i) {
                const __half2* h1 = (const __half2*)&buf[0][i];
                const __half2* h2 = (const __half2*)&buf[1][i];
#pragma unroll
                for (int u = 0; u < 4; ++u) {
                    float2 f1 = __half22float2(h1[u]);
                    float2 f2 = __half22float2(h2[u]);
                    acc0 += f1.x * ps[row][i * 8 + 2 * u] + f1.y * ps[row][i * 8 + 2 * u + 1];
                    acc1 += f2.x * ps[row][i * 8 + 2 * u] + f2.y * ps[row][i * 8 + 2 * u + 1];
                }
            }
            sc[row][l1] = acc0 * INV_SQRT_A;
            sc[row][l2] = acc1 * INV_SQRT_A;
        }
    }
    __syncthreads();

    // ---- Phase B: selection, one row per wave (waves 0..RM-1). R9-proven.
    if (tid < RM * 64) {
        const int w = tid >> 6;
        const int lane = tid & 63;
        const int bb = b0 + w;

        unsigned long long key[16];
#pragma unroll
        for (int j = 0; j < 16; ++j) {
            const int l = j * 64 + lane;
            key[j] = ((unsigned long long)sortable(sc[w][l]) << 10)
                   | (unsigned)(1023 - l);
        }
#pragma unroll
        for (int a = 0; a < 15; ++a)
#pragma unroll
            for (int j = 0; j < 15 - a; ++j) {
                const bool swp = key[j] < key[j + 1];
                const unsigned long long hi = swp ? key[j + 1] : key[j];
                const unsigned long long lo = swp ? key[j] : key[j + 1];
                key[j] = hi; key[j + 1] = lo;
            }

        float myv = -1e30f; int myl = 0;
        unsigned long long front = key[0];
        for (int k = 0; k < TOPK_; ++k) {
            unsigned long long wk = front;
#pragma unroll
            for (int off = 32; off > 0; off >>= 1) {
                unsigned long long o = __shfl_xor(wk, off);
                if (o > wk) wk = o;
            }
            if (lane == k) {
                myv = unsortable((unsigned)(wk >> 10));
                myl = 1023 - (int)(wk & 1023);
            }
            if (front == wk) {
#pragma unroll
                for (int j = 0; j < 15; ++j) key[j] = key[j + 1];
                key[15] = 0ULL;
                front = key[0];
            }
        }

        float m = myv;
#pragma unroll
        for (int off = 32; off > 0; off >>= 1) m = fmaxf(m, __shfl_xor(m, off));
        float e = (lane < TOPK_) ? expf(myv - m) : 0.f;
        float s = e;
#pragma unroll
        for (int off = 32; off > 0; off >>= 1) s += __shfl_xor(s, off);
        if (lane < TOPK_) {
            sw[w][lane]   = e / s;
            stok[w][lane] = seqs[bb * L_ + myl];
        }

        if (lane < E_) {
            float acc = 0.f;
#pragma unroll
            for (int k = 0; k < TOPK_; ++k)
                acc += sw[w][k] * seq_emb[(size_t)stok[w][k] * 32 + lane];
            sc[w][lane] = acc;   // ebar (sc row free now; same-wave r/w)
        }
        if (lane < E_) {
            float acc = bo[lane];
#pragma unroll
            for (int j = 0; j < E_; ++j) acc += sc[w][j] * M[j * E_ + lane];
            fused[bb * 128 + 32 + lane] = acc;   // interest -> global
        }
    }
}

// ---------------------------------------------------------------------------
// K2b: MLP + 2x QNN + out, via v_mfma_f32_16x16x32_f16.
// 64 blocks x 512 thr (8 waves); block owns 16 rows (M=16 tile), wave owns
// 32 output cols (2 N-tiles).  Fragment maps (gfx950, m89-verified family):
//   A[i][k]: i = lane&15, k = 8*(lane>>4) + j   (j = 0..7, half8)
//   B[k][n]: n = lane&15, k = 8*(lane>>4) + j   -> contiguous from WT[n][k]
//   D[i][n]: n = lane&15, i = 4*(lane>>4) + reg
// Activations round-trip through padded LDS (row stride 260 f32 / 264 f16:
// 2-way bank aliasing = free).  t1/t2 stay in C-fragments (aligned layouts)
// so t=(t1+b1)*(t2+b2) is pure register math; proj MFMA's C-in carries the
// residual h.  5 barriers total, ~25 KB LDS.
// ---------------------------------------------------------------------------
#define GR 16
#define HSP 260
#define TSP 264
__global__ __launch_bounds__(512) void mlp_mfma_kernel(
    const float* __restrict__ fused,
    const __half* __restrict__ WmlpT, const float* __restrict__ bmlp,
    const __half* __restrict__ W1T1, const __half* __restrict__ W2T1,
    const __half* __restrict__ WpT1,
    const float* __restrict__ b11, const float* __restrict__ b12,
    const float* __restrict__ b1p,
    const __half* __restrict__ W1T2, const __half* __restrict__ W2T2,
    const __half* __restrict__ WpT2,
    const float* __restrict__ b21, const float* __restrict__ b22,
    const float* __restrict__ b2p,
    const float* __restrict__ Wout, const float* __restrict__ bout,
    float* __restrict__ out)
{
    const int r0 = blockIdx.x * GR;
    const int tid = threadIdx.x;
    const int w = tid >> 6;
    const int l = tid & 63;
    const int lr = l & 15;
    const int lk = l >> 4;
    const int n0 = w * 32;

    __shared__ float hs[GR][HSP];
    __shared__ __half ts_h[GR][TSP];

    f32x4 hC0, hC1;
    const f32x4 zf = {0.f, 0.f, 0.f, 0.f};

    // ---- stage 1: h = relu(x @ Wmlp + bmlp), K = 128
    {
        half8 ax[4];
        const float* xrow = fused + (size_t)(r0 + lr) * 128 + lk * 8;
#pragma unroll
        for (int ks = 0; ks < 4; ++ks) {
            float4 u = *(const float4*)(xrow + ks * 32);
            float4 v = *(const float4*)(xrow + ks * 32 + 4);
            ax[ks] = cvt_h8(u, v);
        }
#pragma unroll
        for (int t = 0; t < 2; ++t) {
            f32x4 c = zf;
            const __half* wb = WmlpT + (size_t)(n0 + 16 * t + lr) * 128 + lk * 8;
#pragma unroll
            for (int ks = 0; ks < 4; ++ks) {
                half8 b = *(const half8*)(wb + ks * 32);
                c = __builtin_amdgcn_mfma_f32_16x16x32_f16(ax[ks], b, c, 0, 0, 0);
            }
            const int j = n0 + 16 * t + lr;
            const float bm = bmlp[j];
#pragma unroll
            for (int r = 0; r < 4; ++r) {
                float vv = fmaxf(c[r] + bm, 0.f);
                if (t == 0) hC0[r] = vv; else hC1[r] = vv;
                hs[4 * lk + r][j] = vv;
            }
        }
    }
    __syncthreads();

    // ---- 2 qnn blocks
#pragma unroll
    for (int q = 0; q < 2; ++q) {
        const __half* W1T = q ? W1T2 : W1T1;
        const __half* W2T = q ? W2T2 : W2T1;
        const __half* WpT = q ? WpT2 : WpT1;
        const float* bb1 = q ? b21 : b11;
        const float* bb2 = q ? b22 : b12;
        const float* bbp = q ? b2p : b1p;

        // h A-fragments from LDS (f32 -> f16)
        half8 ah[8];
#pragma unroll
        for (int ks = 0; ks < 8; ++ks) {
            const float* hr = &hs[lr][ks * 32 + lk * 8];
            float4 u = *(const float4*)hr;
            float4 v = *(const float4*)(hr + 4);
            ah[ks] = cvt_h8(u, v);
        }
        // t1 = h@W1, t2 = h@W2 (C-fragments), t = (t1+b1)*(t2+b2) -> ts_h f16
#pragma unroll
        for (int t = 0; t < 2; ++t) {
            f32x4 t1 = zf, t2 = zf;
            const __half* w1 = W1T + (size_t)(n0 + 16 * t + lr) * 256 + lk * 8;
            const __half* w2 = W2T + (size_t)(n0 + 16 * t + lr) * 256 + lk * 8;
#pragma unroll
            for (int ks = 0; ks < 8; ++ks) {
                half8 b1 = *(const half8*)(w1 + ks * 32);
                t1 = __builtin_amdgcn_mfma_f32_16x16x32_f16(ah[ks], b1, t1, 0, 0, 0);
                half8 b2 = *(const half8*)(w2 + ks * 32);
                t2 = __builtin_amdgcn_mfma_f32_16x16x32_f16(ah[ks], b2, t2, 0, 0, 0);
            }
            const int j = n0 + 16 * t + lr;
            const float v1 = bb1[j], v2 = bb2[j];
#pragma unroll
            for (int r = 0; r < 4; ++r) {
                float tv = (t1[r] + v1) * (t2[r] + v2);
                ts_h[4 * lk + r][j] = __float2half_rn(tv);
            }
        }
        __syncthreads();   // ts ready; also: all ah reads of hs are done

        // proj: h = h + t @ Wp + bp  (C-in carries residual)
        half8 pa[8];
#pragma unroll
        for (int ks = 0; ks < 8; ++ks)
            pa[ks] = *(const half8*)&ts_h[lr][ks * 32 + lk * 8];
#pragma unroll
        for (int t = 0; t < 2; ++t) {
            f32x4 c = (t == 0) ? hC0 : hC1;
            const __half* wp = WpT + (size_t)(n0 + 16 * t + lr) * 256 + lk * 8;
#pragma unroll
            for (int ks = 0; ks < 8; ++ks) {
                half8 b = *(const half8*)(wp + ks * 32);
                c = __builtin_amdgcn_mfma_f32_16x16x32_f16(pa[ks], b, c, 0, 0, 0);
            }
            const int j = n0 + 16 * t + lr;
            const float bp = bbp[j];
#pragma unroll
            for (int r = 0; r < 4; ++r) {
                float vv = c[r] + bp;
                if (t == 0) hC0[r] = vv; else hC1[r] = vv;
                hs[4 * lk + r][j] = vv;
            }
        }
        __syncthreads();   // new h visible for next qnn / final reduce
    }

    // ---- out = hs @ Wout + bout : 32 threads per row, 8 cols each
    {
        const int i = tid >> 5;
        const int seg = tid & 31;
        const int cb = seg * 8;
        float psum = 0.f;
#pragma unroll
        for (int u = 0; u < 8; ++u) psum += hs[i][cb + u] * Wout[cb + u];
#pragma unroll
        for (int off = 16; off > 0; off >>= 1) psum += __shfl_xor(psum, off);
        if (seg == 0) out[r0 + i] = psum + bout[0];
    }
}

// ---------------------------------------------------------------------------
extern "C" void kernel_launch(void* const* d_in, const int* in_sizes, int n_in,
                              void* d_out, int out_size, void* d_ws, size_t ws_size,
                              hipStream_t stream) {
    const int*   cats    = (const int*)d_in[0];
    const float* nums    = (const float*)d_in[1];
    const int*   seqs    = (const int*)d_in[2];
    const int*   tgt_ids = (const int*)d_in[3];
    const float* cat_emb = (const float*)d_in[4];
    const float* seq_emb = (const float*)d_in[5];
    const float* Wnum    = (const float*)d_in[6];
    const float* bnum    = (const float*)d_in[7];
    const float* Wq      = (const float*)d_in[8];
    const float* Wk      = (const float*)d_in[9];
    const float* Wv      = (const float*)d_in[10];
    const float* Wo      = (const float*)d_in[11];
    const float* bo      = (const float*)d_in[12];
    const float* Wpool   = (const float*)d_in[13];
    const float* bpool   = (const float*)d_in[14];
    const float* Wmlp    = (const float*)d_in[15];
    const float* bmlp    = (const float*)d_in[16];
    const float* q1_W1   = (const float*)d_in[17];
    const float* q1_b1   = (const float*)d_in[18];
    const float* q1_W2   = (const float*)d_in[19];
    const float* q1_b2   = (const float*)d_in[20];
    const float* q1_Wp   = (const float*)d_in[21];
    const float* q1_bp   = (const float*)d_in[22];
    const float* q2_W1   = (const float*)d_in[23];
    const float* q2_b1   = (const float*)d_in[24];
    const float* q2_W2   = (const float*)d_in[25];
    const float* q2_b2   = (const float*)d_in[26];
    const float* q2_Wp   = (const float*)d_in[27];
    const float* q2_bp   = (const float*)d_in[28];
    const float* Wout    = (const float*)d_in[29];
    const float* bout    = (const float*)d_in[30];

    // Workspace layout (float-slot offsets); __half pairs pack 2/slot.
    float* ws = (float*)d_ws;
    float*   p       = ws;                         //       0 .. 32768
    float*   fused   = ws + 32768;                 //   32768 .. 163840
    float*   M       = ws + 163840;                //  163840 .. 164864
    __half2* seq_h2  = (__half2*)(ws + 164864);    //  164864 .. 964928
    __half*  WmlpT   = (__half*)(ws + 964928);     //  964928 .. 981312  (32768 h)
    __half*  W1T1    = (__half*)(ws + 981312);     //  981312 .. 1014080 (65536 h)
    __half*  W2T1    = (__half*)(ws + 1014080);    // 1014080 .. 1046848
    __half*  WpT1    = (__half*)(ws + 1046848);    // 1046848 .. 1079616
    __half*  W1T2    = (__half*)(ws + 1079616);    // 1079616 .. 1112384
    __half*  W2T2    = (__half*)(ws + 1112384);    // 1112384 .. 1145152
    __half*  WpT2    = (__half*)(ws + 1145152);    // 1145152 .. 1177920

    float* out = (float*)d_out;

    fused_prep_kernel<<<K1_GRID, 256, 0, stream>>>(
        cats, nums, tgt_ids, cat_emb, Wnum, bnum, Wq, Wk, Wv, Wo,
        Wpool, bpool, seq_emb, Wmlp,
        q1_W1, q1_W2, q1_Wp, q2_W1, q2_W2, q2_Wp,
        p, fused, M, seq_h2,
        WmlpT, W1T1, W2T1, WpT1, W1T2, W2T2, WpT2);

    score_topk_kernel<<<B_ / RM, 512, 0, stream>>>(
        seqs, (const __half*)seq_h2, seq_emb, p, M, bo, fused);

    mlp_mfma_kernel<<<B_ / GR, 512, 0, stream>>>(
        fused, WmlpT, bmlp,
        W1T1, W2T1, WpT1, q1_b1, q1_b2, q1_bp,
        W1T2, W2T2, WpT2, q2_b1, q2_b2, q2_bp,
        Wout, bout, out);
}